// Round 8
// baseline (216.637 us; speedup 1.0000x reference)
//
#include <hip/hip_runtime.h>
#include <stdint.h>

#define N 8192
#define D 256          // elements per row == bytes per fp8 row
#define INV_T 20.0f
#define BM 128
#define BN 128
#define NXB 64         // col-blocks (N/BN)

typedef __attribute__((ext_vector_type(16))) float f32x16;
typedef __attribute__((ext_vector_type(2))) long i64x2;

// Kernel 1: per-row fp32 normalize -> fp8 e4m3 (OCP) copies; c[i]=(e_i.p_i)/T exact fp32.
// Also zeroes out[0] (poisoned 0xAA; reduce kernel atomicAdds into it).
__global__ __launch_bounds__(256) void normalize_kernel(
    const float* __restrict__ e, const float* __restrict__ p, const float* __restrict__ n,
    uint32_t* __restrict__ eb, uint32_t* __restrict__ pb, uint32_t* __restrict__ nb,
    float* __restrict__ cbuf, float* __restrict__ out0) {
  const int tid = threadIdx.x;
  const int wave = tid >> 6, lane = tid & 63;
  const int row = blockIdx.x * 4 + wave;          // one wave per row
  if (blockIdx.x == 0 && tid == 0) out0[0] = 0.0f;

  const float4 ev = ((const float4*)(e + (size_t)row * D))[lane];
  const float4 pv = ((const float4*)(p + (size_t)row * D))[lane];
  const float4 nv = ((const float4*)(n + (size_t)row * D))[lane];

  float sse = ev.x*ev.x + ev.y*ev.y + ev.z*ev.z + ev.w*ev.w;
  float ssp = pv.x*pv.x + pv.y*pv.y + pv.z*pv.z + pv.w*pv.w;
  float ssn = nv.x*nv.x + nv.y*nv.y + nv.z*nv.z + nv.w*nv.w;
  float dep = ev.x*pv.x + ev.y*pv.y + ev.z*pv.z + ev.w*pv.w;
#pragma unroll
  for (int m = 1; m < 64; m <<= 1) {
    sse += __shfl_xor(sse, m);
    ssp += __shfl_xor(ssp, m);
    ssn += __shfl_xor(ssn, m);
    dep += __shfl_xor(dep, m);
  }
  const float se = 1.0f / fmaxf(sqrtf(sse), 1e-8f);
  const float sp = 1.0f / fmaxf(sqrtf(ssp), 1e-8f);
  const float sn = 1.0f / fmaxf(sqrtf(ssn), 1e-8f);

  int ue = __builtin_amdgcn_cvt_pk_fp8_f32(ev.x*se, ev.y*se, 0, false);
  ue     = __builtin_amdgcn_cvt_pk_fp8_f32(ev.z*se, ev.w*se, ue, true);
  int up = __builtin_amdgcn_cvt_pk_fp8_f32(pv.x*sp, pv.y*sp, 0, false);
  up     = __builtin_amdgcn_cvt_pk_fp8_f32(pv.z*sp, pv.w*sp, up, true);
  int un = __builtin_amdgcn_cvt_pk_fp8_f32(nv.x*sn, nv.y*sn, 0, false);
  un     = __builtin_amdgcn_cvt_pk_fp8_f32(nv.z*sn, nv.w*sn, un, true);
  eb[row * 64 + lane] = (uint32_t)ue;
  pb[row * 64 + lane] = (uint32_t)up;
  nb[row * 64 + lane] = (uint32_t)un;

  if (lane == 0) cbuf[row] = dep * se * sp * INV_T;
}

// Kernel 2: 128x128-tile fp8 GEMM (X @ Y^T) with DIRECT global->VGPR fragment loads.
// No LDS staging, no per-k barriers: 32 global_load_dwordx4 (imm-offset) + 64 MFMAs
// per wave, compiler-interleaved with fine-grained vmcnt (the AITER pattern).
// Wave tile 2x2 (64x64/wave): lanes l and l+32 share cachelines (32 lines/inst);
// B rows read 2x/block from L1/L2 (all tiles L2-resident, FETCH stays ~17MB).
__global__ __launch_bounds__(256, 4) void simexp_kernel(
    const uint8_t* __restrict__ eb, const uint8_t* __restrict__ pb,
    const uint8_t* __restrict__ nb, const float* __restrict__ cbuf,
    float* __restrict__ part) {
  __shared__ float cs[BM];             // 512 B only

  const int z = blockIdx.z;
  const uint8_t* __restrict__ A = z ? pb : eb;
  const uint8_t* __restrict__ B = z ? eb : nb;

  const int tid = threadIdx.x;
  const int wave = tid >> 6, lane = tid & 63;
  const int lane31 = lane & 31, half = lane >> 5;
  const int wr = wave & 1, wc = wave >> 1;
  const int rowTile = blockIdx.x * BM, colblk = blockIdx.y;
  const int colTile = colblk * BN;

  if (tid < BM) cs[tid] = cbuf[rowTile + tid];
  __syncthreads();                     // publish cs (the only barrier)

  // Lane-fixed base addresses; all k-offsets are 13-bit immediates (< 256).
  const uint8_t* arow0 = A + (size_t)(rowTile + wr * 64 + lane31) * D + half * 32;
  const uint8_t* arow1 = arow0 + (size_t)32 * D;
  const uint8_t* brow0 = B + (size_t)(colTile + wc * 64 + lane31) * D + half * 32;
  const uint8_t* brow1 = brow0 + (size_t)32 * D;

  f32x16 acc[2][2];
#pragma unroll
  for (int mi = 0; mi < 2; ++mi)
#pragma unroll
    for (int ni = 0; ni < 2; ++ni)
#pragma unroll
      for (int r = 0; r < 16; ++r) acc[mi][ni][r] = 0.0f;

  // K loop: k-octet for this lane = k0i*64 + half*32 + g*16 (halves split each 64B).
#pragma unroll
  for (int k0i = 0; k0i < 4; ++k0i) {
#pragma unroll
    for (int g = 0; g < 2; ++g) {
      const int koff = k0i * 64 + g * 16;
      const i64x2 a0 = *(const i64x2*)(arow0 + koff);
      const i64x2 a1 = *(const i64x2*)(arow1 + koff);
      const i64x2 b0 = *(const i64x2*)(brow0 + koff);
      const i64x2 b1 = *(const i64x2*)(brow1 + koff);
      acc[0][0] = __builtin_amdgcn_mfma_f32_32x32x16_fp8_fp8(a0.x, b0.x, acc[0][0], 0, 0, 0);
      acc[0][1] = __builtin_amdgcn_mfma_f32_32x32x16_fp8_fp8(a0.x, b1.x, acc[0][1], 0, 0, 0);
      acc[1][0] = __builtin_amdgcn_mfma_f32_32x32x16_fp8_fp8(a1.x, b0.x, acc[1][0], 0, 0, 0);
      acc[1][1] = __builtin_amdgcn_mfma_f32_32x32x16_fp8_fp8(a1.x, b1.x, acc[1][1], 0, 0, 0);
      acc[0][0] = __builtin_amdgcn_mfma_f32_32x32x16_fp8_fp8(a0.y, b0.y, acc[0][0], 0, 0, 0);
      acc[0][1] = __builtin_amdgcn_mfma_f32_32x32x16_fp8_fp8(a0.y, b1.y, acc[0][1], 0, 0, 0);
      acc[1][0] = __builtin_amdgcn_mfma_f32_32x32x16_fp8_fp8(a1.y, b0.y, acc[1][0], 0, 0, 0);
      acc[1][1] = __builtin_amdgcn_mfma_f32_32x32x16_fp8_fp8(a1.y, b1.y, acc[1][1], 0, 0, 0);
    }
  }

  // Epilogue. 32x32 C/D: col=lane&31, row=(reg&3)+8*(reg>>2)+4*half (m74/m101).
  // Wave (wr,wc) covers rows wr*64+mi*32+rlocal, cols colTile+wc*64+ni*32+lane31.
#pragma unroll
  for (int mi = 0; mi < 2; ++mi) {
#pragma unroll
    for (int reg = 0; reg < 16; ++reg) {
      const int rlocal = (reg & 3) + 8 * (reg >> 2) + 4 * half;
      const int rowl = wr * 64 + mi * 32 + rlocal;
      const float cv = cs[rowl];
      float v = __expf(acc[mi][0][reg] * INV_T - cv) +
                __expf(acc[mi][1][reg] * INV_T - cv);
      v += __shfl_xor(v, 1);
      v += __shfl_xor(v, 2);
      v += __shfl_xor(v, 4);
      v += __shfl_xor(v, 8);
      v += __shfl_xor(v, 16);
      if (lane31 == 0)
        part[((size_t)(z * 2 * NXB + colblk * 2 + wc)) * N + rowTile + rowl] = v;
    }
  }
}

// Kernel 3: per-row sum of 128 partials -> log/log1p -> block reduce -> atomicAdd(out).
// 256 blocks; block handles 64 row-items; (tid&63)=item, (tid>>6)=quarter of x-range.
__global__ __launch_bounds__(256) void reduce_kernel(const float* __restrict__ part,
                                                     float* __restrict__ out) {
  __shared__ float sm[64][4];
  const int tid = threadIdx.x;
  const int item0 = blockIdx.x * 64;               // items: z*N + row, 16384 total
  const int il = tid & 63, seg = tid >> 6;
  const int item = item0 + il;
  const int z = item >> 13, row = item & (N - 1);
  float s = 0.0f;
#pragma unroll
  for (int x = seg * 32; x < seg * 32 + 32; ++x)
    s += part[((size_t)(z * 2 * NXB + x)) * N + row];
  sm[il][seg] = s;
  __syncthreads();
  if (tid < 64) {
    const float t = sm[tid][0] + sm[tid][1] + sm[tid][2] + sm[tid][3];
    const int zz = (item0 + tid) >> 13;
    float val = zz ? logf(t) : log1pf(t);
#pragma unroll
    for (int m = 1; m < 64; m <<= 1) val += __shfl_xor(val, m);
    if (tid == 0) atomicAdd(out, val * (1.0f / (float)N));
  }
}

extern "C" void kernel_launch(void* const* d_in, const int* in_sizes, int n_in,
                              void* d_out, int out_size, void* d_ws, size_t ws_size,
                              hipStream_t stream) {
  const float* e = (const float*)d_in[0];
  const float* p = (const float*)d_in[1];
  const float* n = (const float*)d_in[2];

  char* w = (char*)d_ws;
  uint8_t* eb = (uint8_t*)w;                                     // 2 MB
  uint8_t* pb = eb + (size_t)N * D;                              // 2 MB
  uint8_t* nb = pb + (size_t)N * D;                              // 2 MB
  float* cbuf = (float*)(nb + (size_t)N * D);                    // 32 KB
  float* part = cbuf + N;                                        // 2*128*8192*4 = 8 MB
  float* out = (float*)d_out;

  normalize_kernel<<<N / 4, 256, 0, stream>>>(e, p, n, (uint32_t*)eb, (uint32_t*)pb,
                                              (uint32_t*)nb, cbuf, out);
  simexp_kernel<<<dim3(N / BM, N / BN, 2), 256, 0, stream>>>(eb, pb, nb, cbuf, part);
  reduce_kernel<<<256, 256, 0, stream>>>(part, out);
}